// Round 4
// baseline (158.969 us; speedup 1.0000x reference)
//
#include <hip/hip_runtime.h>

// StereoCostVolume: c1, warp [B=8, H=192, W=640, C=64] f32.
// out [B,H,W,69]: out[...,0:64] = c1; out[...,64+d] = mean_c(c1[w] * warp[w+d-2]), zero-padded in W.
//
// Block = 512 threads handles a 64-pixel row tile.
// Thread t: chan4 = t&15 (4 channels), pixels {t>>4, (t>>4)+32}.
// - c1 AND warp read directly from global (all loads coalesced 1KB/wave; the 5x
//   warp overlap is absorbed by L1/L2 — per-block window is only ~17KB).
// - partial dots (4ch) reduced across 16 lanes via DPP row_shl adds (VALU pipe, no DS);
//   row_shl pulls from lane i+N, so the FULL sum lands in lane 0 of each 16-lane row.
// - output tile assembled in LDS, stored as linear 16B-aligned float4 stream.
// - ONE barrier total (assembly -> linear store). No staging phase.

#define WIDTH 640
#define CH 64
#define NOFF 5
#define OUTC 69
#define TILE_PIX 64
#define BDIM 512
#define TILES_PER_ROW (WIDTH / TILE_PIX)      // 10
#define NROWS (8 * 192)                       // 1536
#define OUT_F4 (TILE_PIX * OUTC / 4)          // 1104 float4 = 17664 B

__device__ __forceinline__ float row_reduce_sum16_lane0(float v) {
    union { float f; int i; } a, b;
    a.f = v;
    // row_shl:N = dpp_ctrl 0x100+N: lane i reads lane i+N (OOB -> 0 with bound_ctrl).
    b.i = __builtin_amdgcn_update_dpp(0, a.i, 0x101, 0xF, 0xF, true); a.f += b.f;
    b.i = __builtin_amdgcn_update_dpp(0, a.i, 0x102, 0xF, 0xF, true); a.f += b.f;
    b.i = __builtin_amdgcn_update_dpp(0, a.i, 0x104, 0xF, 0xF, true); a.f += b.f;
    b.i = __builtin_amdgcn_update_dpp(0, a.i, 0x108, 0xF, 0xF, true); a.f += b.f;
    return a.f;  // lane 0 of each 16-lane row holds the full 16-lane sum
}

__global__ __launch_bounds__(BDIM) void StereoCostVolume_kernel(
    const float* __restrict__ c1,
    const float* __restrict__ warp,
    float* __restrict__ out)
{
    __shared__ float4 lds[OUT_F4];   // out tile only

    const int t   = threadIdx.x;
    const int bx  = blockIdx.x;
    const int tw  = bx % TILES_PER_ROW;
    const int row = bx / TILES_PER_ROW;          // b*H + h
    const int w0  = tw * TILE_PIX;
    const int pix0 = row * WIDTH + w0;           // global pixel index of tile start

    const float4* c1f4   = (const float4*)c1;
    const float4* warpf4 = (const float4*)warp;

    const int c4 = t & 15;      // chan4 group
    const int p0 = t >> 4;      // local pixel [0,32); also handles p0+32

    // c1 for this thread's 2 pixels (coalesced: each wave reads contiguous 1KB)
    const float4 a0 = c1f4[(pix0 + p0) * 16 + c4];
    const float4 a1 = c1f4[(pix0 + p0 + 32) * 16 + c4];

    // ---- 5 correlations per pixel, warp read straight from global ----
    float s[2][NOFF];
    #pragma unroll
    for (int j = 0; j < 2; ++j) {
        const int p = p0 + 32 * j;
        const int w = w0 + p;
        const float4 a = (j == 0) ? a0 : a1;
        #pragma unroll
        for (int d = 0; d < NOFF; ++d) {
            const int ww = w + d - 2;
            float acc = 0.0f;
            if (ww >= 0 && ww < WIDTH) {
                const float4 b = warpf4[(row * WIDTH + ww) * 16 + c4];  // coalesced 1KB/wave
                acc = a.x * b.x + a.y * b.y + a.z * b.z + a.w * b.w;
            }
            s[j][d] = row_reduce_sum16_lane0(acc);
        }
    }

    // ---- assemble output tile in LDS ----
    {
        float* ldsw = (float*)lds;
        #pragma unroll
        for (int j = 0; j < 2; ++j) {
            const int p = p0 + 32 * j;
            const float4 a = (j == 0) ? a0 : a1;
            const int base = p * OUTC + c4 * 4;
            ldsw[base + 0] = a.x;
            ldsw[base + 1] = a.y;
            ldsw[base + 2] = a.z;
            ldsw[base + 3] = a.w;
        }
        if ((t & 15) == 0) {
            #pragma unroll
            for (int j = 0; j < 2; ++j) {
                const int p = p0 + 32 * j;
                #pragma unroll
                for (int d = 0; d < NOFF; ++d)
                    ldsw[p * OUTC + CH + d] = s[j][d] * (1.0f / 64.0f);
            }
        }
    }
    __syncthreads();

    // ---- linear coalesced store of the out tile (16B-aligned: pix0*69*4 % 16 == 0) ----
    {
        float4* outf4 = (float4*)out;
        const int obase = (pix0 * OUTC) >> 2;    // pix0 multiple of 64 -> exact
        #pragma unroll
        for (int r = 0; r < 3; ++r) {
            const int idx = t + r * BDIM;
            if (idx < OUT_F4) outf4[obase + idx] = lds[idx];
        }
    }
}

extern "C" void kernel_launch(void* const* d_in, const int* in_sizes, int n_in,
                              void* d_out, int out_size, void* d_ws, size_t ws_size,
                              hipStream_t stream) {
    const float* c1   = (const float*)d_in[0];
    const float* warp = (const float*)d_in[1];
    float* out = (float*)d_out;

    const int grid = NROWS * TILES_PER_ROW;   // 15360 blocks
    StereoCostVolume_kernel<<<grid, BDIM, 0, stream>>>(c1, warp, out);
}

// Round 5
// 138.532 us; speedup vs baseline: 1.1475x; 1.1475x over previous
//
#include <hip/hip_runtime.h>

// StereoCostVolume: c1, warp [B=8, H=192, W=640, C=64] f32.
// out [B,H,W,69]: out[...,0:64] = c1; out[...,64+d] = mean_c(c1[w] * warp[w+d-2]), zero-padded in W.
//
// Wave-autonomous, ZERO-barrier design. Each wave owns 4-pixel groups:
//   lane = (px = l>>4, c4 = l&15): 4 channels of one of 4 pixels.
// Per group: coalesced c1 load (1KB/wave), 5 coalesced warp loads (cache absorbs
// the 5x overlap), 16-lane DPP row_shl reduction (VALU pipe), then the 1104B
// output record (4 px x 69 floats = exactly 69 float4s, 16B-aligned) is
// assembled in a PRIVATE per-wave LDS slice and streamed out as float4s.
// No __syncthreads anywhere: LDS ops of one wave complete in order; the
// read-back only needs lgkmcnt (compiler-inserted). Waves never couple.
// Nontemporal on c1 load / out store keeps L2 for the 5x-reused warp stream.

typedef float f32x4 __attribute__((ext_vector_type(4)));

#define WIDTH 640
#define CH 64
#define NOFF 5
#define OUTC 69
#define GPX 4                           // pixels per group
#define REC_F4 ((GPX * OUTC) / 4)       // 69 float4 per group record (1104 B)
#define NPIX (8 * 192 * 640)            // 983040
#define NGROUPS (NPIX / GPX)            // 245760
#define BDIM 256
#define WPB (BDIM / 64)                 // 4 waves/block
#define GPW 2                           // groups per wave
#define NBLOCKS (NGROUPS / (WPB * GPW)) // 30720
#define GROUPS_PER_ROW (WIDTH / GPX)    // 160 (even -> a wave's 2 groups never straddle a row)

__device__ __forceinline__ float row_reduce_sum16_lane0(float v) {
    union { float f; int i; } a, b;
    a.f = v;
    // row_shl:N (0x100+N): lane i reads lane i+N within its 16-lane row (OOB -> 0).
    b.i = __builtin_amdgcn_update_dpp(0, a.i, 0x101, 0xF, 0xF, true); a.f += b.f;
    b.i = __builtin_amdgcn_update_dpp(0, a.i, 0x102, 0xF, 0xF, true); a.f += b.f;
    b.i = __builtin_amdgcn_update_dpp(0, a.i, 0x104, 0xF, 0xF, true); a.f += b.f;
    b.i = __builtin_amdgcn_update_dpp(0, a.i, 0x108, 0xF, 0xF, true); a.f += b.f;
    return a.f;  // lane 0 of each 16-lane row holds the full 16-lane sum
}

__global__ __launch_bounds__(BDIM) void StereoCostVolume_kernel(
    const float* __restrict__ c1,
    const float* __restrict__ warp,
    float* __restrict__ out)
{
    __shared__ f32x4 lds[WPB * GPW * REC_F4];   // 8832 B/block -> occupancy capped by waves, not LDS

    const int t   = threadIdx.x;
    const int wid = t >> 6;         // wave in block
    const int l   = t & 63;
    const int px  = l >> 4;         // local pixel in group
    const int c4  = l & 15;         // channel quad

    const f32x4* c1f4   = (const f32x4*)c1;
    const f32x4* warpf4 = (const f32x4*)warp;
    f32x4*       outf4  = (f32x4*)out;

    const int gwave = blockIdx.x * WPB + wid;

    #pragma unroll
    for (int it = 0; it < GPW; ++it) {
        const int g   = gwave * GPW + it;            // 2 consecutive groups/wave (halo reuse)
        const int row = g / GROUPS_PER_ROW;
        const int gw  = g - row * GROUPS_PER_ROW;
        const int w   = gw * GPX + px;               // this lane's width coordinate
        const int pix = g * GPX + px;

        const f32x4 a = __builtin_nontemporal_load(&c1f4[pix * 16 + c4]);

        float s0, s1, s2, s3, s4;
        const int wbase = (row * WIDTH + w) * 16 + c4;
        #pragma unroll
        for (int d = 0; d < NOFF; ++d) {
            const int ww = w + d - 2;
            float acc = 0.0f;
            if (ww >= 0 && ww < WIDTH) {
                const f32x4 b = warpf4[wbase + (d - 2) * 16];   // coalesced 1KB/wave
                acc = a.x * b.x + a.y * b.y + a.z * b.z + a.w * b.w;
            }
            const float r = row_reduce_sum16_lane0(acc);
            if      (d == 0) s0 = r;
            else if (d == 1) s1 = r;
            else if (d == 2) s2 = r;
            else if (d == 3) s3 = r;
            else             s4 = r;
        }

        // ---- assemble this wave's 1104B record in its private LDS slice ----
        float* rec = (float*)&lds[(wid * GPW + it) * REC_F4];
        const int fb = px * OUTC + c4 * 4;
        rec[fb + 0] = a.x;   // 2-way bank aliasing only (free)
        rec[fb + 1] = a.y;
        rec[fb + 2] = a.z;
        rec[fb + 3] = a.w;
        if (c4 == 0) {
            rec[px * OUTC + CH + 0] = s0 * 0.015625f;
            rec[px * OUTC + CH + 1] = s1 * 0.015625f;
            rec[px * OUTC + CH + 2] = s2 * 0.015625f;
            rec[px * OUTC + CH + 3] = s3 * 0.015625f;
            rec[px * OUTC + CH + 4] = s4 * 0.015625f;
        }
        __builtin_amdgcn_wave_barrier();   // compile-time only: keep reads after writes

        // ---- linear 16B-aligned coalesced store: record base = g*1104, 1104 = 69*16 ----
        const f32x4* recf4 = (const f32x4*)rec;
        #pragma unroll
        for (int r2 = 0; r2 < 2; ++r2) {
            const int idx = l + 64 * r2;
            if (idx < REC_F4)
                __builtin_nontemporal_store(recf4[idx], &outf4[g * REC_F4 + idx]);
        }
    }
}

extern "C" void kernel_launch(void* const* d_in, const int* in_sizes, int n_in,
                              void* d_out, int out_size, void* d_ws, size_t ws_size,
                              hipStream_t stream) {
    const float* c1   = (const float*)d_in[0];
    const float* warp = (const float*)d_in[1];
    float* out = (float*)d_out;

    StereoCostVolume_kernel<<<NBLOCKS, BDIM, 0, stream>>>(c1, warp, out);
}

// Round 6
// 126.628 us; speedup vs baseline: 1.2554x; 1.0940x over previous
//
#include <hip/hip_runtime.h>

// StereoCostVolume: c1, warp [B=8, H=192, W=640, C=64] f32.
// out [B,H,W,69]: out[...,0:64] = c1; out[...,64+d] = mean_c(c1[w] * warp[w+d-2]), zero-padded in W.
//
// Wave-autonomous, zero-block-barrier design (R5 structure) + R6 scheduling fix:
// - Each wave owns 2 consecutive 4-pixel groups in one row (lane = (px = l>>4, c4 = l&15)).
// - WAVE-UNIFORM interior/edge split: 78/80 waves take a branch-free path where all
//   12 float4 loads (2x c1 + 2x5 warp) issue back-to-back up front -> one vmcnt
//   shadow, 12KB MLP per wave. Edge waves (gw 0 / 159) take the guarded path.
// - 16-lane DPP row_shl reduction (VALU pipe, no DS, full sum -> lane 0).
// - 1104B/group output record assembled in a private per-wave LDS slice (no
//   __syncthreads anywhere; per-wave LDS ordering + lgkmcnt suffices), then
//   streamed out as 16B-aligned float4s.
// - Cache policy (measured R5: FETCH 260MB ~= c1 only, warp L3-resident):
//   nontemporal on c1 load + out store, plain loads for warp. Keep.

typedef float f32x4 __attribute__((ext_vector_type(4)));

#define WIDTH 640
#define CH 64
#define NOFF 5
#define OUTC 69
#define GPX 4                           // pixels per group
#define REC_F4 ((GPX * OUTC) / 4)       // 69 float4 per group record (1104 B)
#define NPIX (8 * 192 * 640)            // 983040
#define NGROUPS (NPIX / GPX)            // 245760
#define BDIM 256
#define WPB (BDIM / 64)                 // 4 waves/block
#define GPW 2                           // groups per wave (same row: 160 even)
#define NBLOCKS (NGROUPS / (WPB * GPW)) // 30720
#define GROUPS_PER_ROW (WIDTH / GPX)    // 160

__device__ __forceinline__ float row_reduce_sum16_lane0(float v) {
    union { float f; int i; } a, b;
    a.f = v;
    // row_shl:N (0x100+N): lane i reads lane i+N within its 16-lane row (OOB -> 0).
    b.i = __builtin_amdgcn_update_dpp(0, a.i, 0x101, 0xF, 0xF, true); a.f += b.f;
    b.i = __builtin_amdgcn_update_dpp(0, a.i, 0x102, 0xF, 0xF, true); a.f += b.f;
    b.i = __builtin_amdgcn_update_dpp(0, a.i, 0x104, 0xF, 0xF, true); a.f += b.f;
    b.i = __builtin_amdgcn_update_dpp(0, a.i, 0x108, 0xF, 0xF, true); a.f += b.f;
    return a.f;  // lane 0 of each 16-lane row holds the full 16-lane sum
}

__global__ __launch_bounds__(BDIM) void StereoCostVolume_kernel(
    const float* __restrict__ c1,
    const float* __restrict__ warp,
    float* __restrict__ out)
{
    __shared__ f32x4 lds[WPB * GPW * REC_F4];   // 8832 B/block

    const int t   = threadIdx.x;
    const int wid = t >> 6;
    const int l   = t & 63;
    const int px  = l >> 4;         // local pixel in group
    const int c4  = l & 15;         // channel quad

    const f32x4* c1f4   = (const f32x4*)c1;
    const f32x4* warpf4 = (const f32x4*)warp;
    f32x4*       outf4  = (f32x4*)out;

    const int gwave = blockIdx.x * WPB + wid;
    const int g0    = gwave * GPW;                 // even; g0,g0+1 share a row
    const int row   = g0 / GROUPS_PER_ROW;
    const int gw0   = g0 - row * GROUPS_PER_ROW;   // even, in [0,158]

    const int w0 = gw0 * GPX + px;                 // group0 lane width coord
    const int i0 = (g0 * GPX + px) * 16 + c4;      // c1/out f4 index, group0
    const int wb0 = (row * WIDTH + w0) * 16 + c4;  // warp f4 index at offset 0

    // ---- load phase: all 12 float4 loads up front ----
    const f32x4 a0 = __builtin_nontemporal_load(&c1f4[i0]);
    const f32x4 a1 = __builtin_nontemporal_load(&c1f4[i0 + GPX * 16]);

    f32x4 b0[NOFF], b1[NOFF];
    if (gw0 != 0 && gw0 != GROUPS_PER_ROW - 2) {
        // interior (wave-uniform): branch-free, back-to-back issue
        #pragma unroll
        for (int d = 0; d < NOFF; ++d) {
            b0[d] = warpf4[wb0 + (d - 2) * 16];
            b1[d] = warpf4[wb0 + (d - 2) * 16 + GPX * 16];
        }
    } else {
        // row-edge waves (2 per row): per-lane guarded loads
        #pragma unroll
        for (int d = 0; d < NOFF; ++d) {
            const int ww0 = w0 + d - 2;
            const int ww1 = ww0 + GPX;
            b0[d] = (ww0 >= 0 && ww0 < WIDTH) ? warpf4[wb0 + (d - 2) * 16]
                                              : f32x4{0.f, 0.f, 0.f, 0.f};
            b1[d] = (ww1 >= 0 && ww1 < WIDTH) ? warpf4[wb0 + (d - 2) * 16 + GPX * 16]
                                              : f32x4{0.f, 0.f, 0.f, 0.f};
        }
    }

    // ---- compute: 10 independent dot4 + DPP reduce chains ----
    float s0[NOFF], s1[NOFF];
    #pragma unroll
    for (int d = 0; d < NOFF; ++d) {
        const float acc0 = a0.x * b0[d].x + a0.y * b0[d].y + a0.z * b0[d].z + a0.w * b0[d].w;
        const float acc1 = a1.x * b1[d].x + a1.y * b1[d].y + a1.z * b1[d].z + a1.w * b1[d].w;
        s0[d] = row_reduce_sum16_lane0(acc0);
        s1[d] = row_reduce_sum16_lane0(acc1);
    }

    // ---- assemble both 1104B records in private LDS slices ----
    float* rec0 = (float*)&lds[(wid * GPW + 0) * REC_F4];
    float* rec1 = (float*)&lds[(wid * GPW + 1) * REC_F4];
    const int fb = px * OUTC + c4 * 4;
    rec0[fb + 0] = a0.x; rec0[fb + 1] = a0.y; rec0[fb + 2] = a0.z; rec0[fb + 3] = a0.w;
    rec1[fb + 0] = a1.x; rec1[fb + 1] = a1.y; rec1[fb + 2] = a1.z; rec1[fb + 3] = a1.w;
    if (c4 == 0) {
        #pragma unroll
        for (int d = 0; d < NOFF; ++d) {
            rec0[px * OUTC + CH + d] = s0[d] * 0.015625f;
            rec1[px * OUTC + CH + d] = s1[d] * 0.015625f;
        }
    }
    __builtin_amdgcn_wave_barrier();   // compile-time fence: keep reads after writes

    // ---- linear 16B-aligned coalesced stores (record base g*1104B) ----
    {
        const f32x4* r0 = (const f32x4*)rec0;
        const f32x4* r1 = (const f32x4*)rec1;
        const int ob0 = g0 * REC_F4;
        __builtin_nontemporal_store(r0[l], &outf4[ob0 + l]);
        __builtin_nontemporal_store(r1[l], &outf4[ob0 + REC_F4 + l]);
        if (l < REC_F4 - 64) {
            __builtin_nontemporal_store(r0[64 + l], &outf4[ob0 + 64 + l]);
            __builtin_nontemporal_store(r1[64 + l], &outf4[ob0 + REC_F4 + 64 + l]);
        }
    }
}

extern "C" void kernel_launch(void* const* d_in, const int* in_sizes, int n_in,
                              void* d_out, int out_size, void* d_ws, size_t ws_size,
                              hipStream_t stream) {
    const float* c1   = (const float*)d_in[0];
    const float* warp = (const float*)d_in[1];
    float* out = (float*)d_out;

    StereoCostVolume_kernel<<<NBLOCKS, BDIM, 0, stream>>>(c1, warp, out);
}

// Round 7
// 125.432 us; speedup vs baseline: 1.2674x; 1.0095x over previous
//
#include <hip/hip_runtime.h>

// StereoCostVolume: c1, warp [B=8, H=192, W=640, C=64] f32.
// out [B,H,W,69]: out[...,0:64] = c1; out[...,64+d] = mean_c(c1[w] * warp[w+d-2]), zero-padded in W.
//
// R7: wave-autonomous (zero block barriers) + per-wave software pipeline.
// Each wave owns 8 CONSECUTIVE group-pairs (64 pixels) in one row.
//   lane = (px = l>>4, c4 = l&15); pair = 2 groups of 4 pixels = 8 px.
// Per iteration: 12 coalesced float4 loads (2 c1 + 10 warp), 10 dot4 + DPP
// row_shl 16-lane reductions, 2208B record assembled in a private per-wave LDS
// slice, streamed out as 16B-aligned float4s.
// 2-deep register double-buffer (X/Y): iter i+1's loads issue BEFORE iter i's
// compute -> memory in flight ~continuously. 3840 blocks (8x fewer dispatches).
// Addressing: warp base == c1 base (row*640+8*rp+px == pair*8+px), so every
// load is base0 + it*128 (+64 group1, +(d-2)*16 offset).
// Edge guards fold to compile time: pairs/row=80, 8 pairs/wave -> left edge
// only at it==0 (rp0==0), right edge only at it==7 (rp0==72).
// Cache policy (R5 evidence: FETCH 260MB ~= c1 only, warp stays L3-resident):
// nontemporal c1 loads + out stores, plain warp loads.

typedef float f32x4 __attribute__((ext_vector_type(4)));

#define WIDTH 640
#define CH 64
#define NOFF 5
#define OUTC 69
#define REC_F4 69                        // float4 per 4-pixel record (1104 B)
#define NPIX (8 * 192 * 640)             // 983040
#define NPAIR (NPIX / 8)                 // 122880 pairs (8 px each)
#define NITER 8                          // pairs per wave
#define BDIM 256
#define WPB (BDIM / 64)                  // 4 waves/block
#define NBLOCKS (NPAIR / (WPB * NITER))  // 3840
#define PAIRS_PER_ROW (WIDTH / 8)        // 80 (multiple of NITER -> no row straddle)

__device__ __forceinline__ float row_reduce_sum16_lane0(float v) {
    union { float f; int i; } a, b;
    a.f = v;
    // row_shl:N (0x100+N): lane i reads lane i+N within its 16-lane row (OOB -> 0).
    b.i = __builtin_amdgcn_update_dpp(0, a.i, 0x101, 0xF, 0xF, true); a.f += b.f;
    b.i = __builtin_amdgcn_update_dpp(0, a.i, 0x102, 0xF, 0xF, true); a.f += b.f;
    b.i = __builtin_amdgcn_update_dpp(0, a.i, 0x104, 0xF, 0xF, true); a.f += b.f;
    b.i = __builtin_amdgcn_update_dpp(0, a.i, 0x108, 0xF, 0xF, true); a.f += b.f;
    return a.f;  // lane 0 of each 16-lane row holds the full 16-lane sum
}

struct Frag {
    f32x4 a0, a1;
    f32x4 b0[NOFF], b1[NOFF];
};

__global__ __launch_bounds__(BDIM) void StereoCostVolume_kernel(
    const float* __restrict__ c1,
    const float* __restrict__ warp,
    float* __restrict__ out)
{
    __shared__ f32x4 lds[WPB * 2 * REC_F4];   // 8832 B/block

    const int t   = threadIdx.x;
    const int wid = t >> 6;
    const int l   = t & 63;
    const int px  = l >> 4;
    const int c4  = l & 15;

    const f32x4* c1f4   = (const f32x4*)c1;
    const f32x4* warpf4 = (const f32x4*)warp;
    f32x4*       outf4  = (f32x4*)out;

    const int wave  = blockIdx.x * WPB + wid;
    const int pbase = wave * NITER;                 // first pair
    const int rp0   = pbase % PAIRS_PER_ROW;        // in-row pair idx of iter 0 (multiple of 8)
    const bool leftw  = (rp0 == 0);
    const bool rightw = (rp0 == PAIRS_PER_ROW - NITER);

    const int base0 = (pbase * 8 + px) * 16 + c4;   // f4 idx into c1 AND warp, iter 0 group 0

    float* rec0w = (float*)&lds[(wid * 2 + 0) * REC_F4];
    float* rec1w = (float*)&lds[(wid * 2 + 1) * REC_F4];
    const f32x4* rec0r = (const f32x4*)rec0w;
    const f32x4* rec1r = (const f32x4*)rec1w;

    auto LOAD = [&](int it, Frag& F) {
        const int base = base0 + it * 128;
        F.a0 = __builtin_nontemporal_load(&c1f4[base]);
        F.a1 = __builtin_nontemporal_load(&c1f4[base + 64]);
        const bool edge = (leftw && it == 0) || (rightw && it == NITER - 1);
        if (!edge) {
            #pragma unroll
            for (int d = 0; d < NOFF; ++d) {
                F.b0[d] = warpf4[base + (d - 2) * 16];
                F.b1[d] = warpf4[base + 64 + (d - 2) * 16];
            }
        } else {
            const int w0 = (rp0 + it) * 8 + px;     // lane width coord, group 0
            #pragma unroll
            for (int d = 0; d < NOFF; ++d) {
                const int ww0 = w0 + d - 2;
                const int ww1 = ww0 + 4;
                F.b0[d] = (ww0 >= 0 && ww0 < WIDTH) ? warpf4[base + (d - 2) * 16]
                                                    : f32x4{0.f, 0.f, 0.f, 0.f};
                F.b1[d] = (ww1 >= 0 && ww1 < WIDTH) ? warpf4[base + 64 + (d - 2) * 16]
                                                    : f32x4{0.f, 0.f, 0.f, 0.f};
            }
        }
    };

    auto PROC = [&](int it, const Frag& F) {
        float s0[NOFF], s1[NOFF];
        #pragma unroll
        for (int d = 0; d < NOFF; ++d) {
            const float acc0 = F.a0.x * F.b0[d].x + F.a0.y * F.b0[d].y
                             + F.a0.z * F.b0[d].z + F.a0.w * F.b0[d].w;
            const float acc1 = F.a1.x * F.b1[d].x + F.a1.y * F.b1[d].y
                             + F.a1.z * F.b1[d].z + F.a1.w * F.b1[d].w;
            s0[d] = row_reduce_sum16_lane0(acc0);
            s1[d] = row_reduce_sum16_lane0(acc1);
        }
        const int fb = px * OUTC + c4 * 4;
        rec0w[fb + 0] = F.a0.x; rec0w[fb + 1] = F.a0.y;
        rec0w[fb + 2] = F.a0.z; rec0w[fb + 3] = F.a0.w;
        rec1w[fb + 0] = F.a1.x; rec1w[fb + 1] = F.a1.y;
        rec1w[fb + 2] = F.a1.z; rec1w[fb + 3] = F.a1.w;
        if (c4 == 0) {
            #pragma unroll
            for (int d = 0; d < NOFF; ++d) {
                rec0w[px * OUTC + CH + d] = s0[d] * 0.015625f;
                rec1w[px * OUTC + CH + d] = s1[d] * 0.015625f;
            }
        }
        __builtin_amdgcn_wave_barrier();   // compile-time fence: reads after writes

        const int ob = (pbase + it) * (2 * REC_F4);
        __builtin_nontemporal_store(rec0r[l], &outf4[ob + l]);
        __builtin_nontemporal_store(rec1r[l], &outf4[ob + REC_F4 + l]);
        if (l < REC_F4 - 64) {
            __builtin_nontemporal_store(rec0r[64 + l], &outf4[ob + 64 + l]);
            __builtin_nontemporal_store(rec1r[64 + l], &outf4[ob + REC_F4 + 64 + l]);
        }
        __builtin_amdgcn_wave_barrier();   // keep next iter's LDS writes after these reads
    };

    Frag X, Y;
    LOAD(0, X);
    #pragma unroll
    for (int ii = 0; ii < NITER; ii += 2) {
        LOAD(ii + 1, Y);
        PROC(ii, X);
        if (ii + 2 < NITER) LOAD(ii + 2, X);
        PROC(ii + 1, Y);
    }
}

extern "C" void kernel_launch(void* const* d_in, const int* in_sizes, int n_in,
                              void* d_out, int out_size, void* d_ws, size_t ws_size,
                              hipStream_t stream) {
    const float* c1   = (const float*)d_in[0];
    const float* warp = (const float*)d_in[1];
    float* out = (float*)d_out;

    StereoCostVolume_kernel<<<NBLOCKS, BDIM, 0, stream>>>(c1, warp, out);
}